// Round 6
// baseline (187.880 us; speedup 1.0000x reference)
//
#include <hip/hip_runtime.h>

// Depthwise 11x11 box blur, reflect pad, fp32, (16,64,256,256).
// Separable, register-resident vertical ring + shuffle horizontal.
// NO LDS data plane, NO barriers.
//
// Round-6 change (single lever): wave strip 64 -> 32 rows, grid 1024 -> 2048
// blocks (block = 4 waves = half an image). Round 5 was grid-limited to
// 4 blocks/CU (Occupancy 39%) with only ~32KB/CU of loads in flight; this
// doubles resident waves to 8 blocks/CU (32 waves/CU, ~64KB/CU in flight).
// __launch_bounds__(256,8) pins VGPR <= 64 so 8 blocks/CU actually fit.
//
// Vertical: 11-deep float4 register ring, fully unrolled (static indices),
//           2-deep explicit load prefetch. Reads/byte = 42/32 = 1.31x
//           (halo rows are L3-resident; input fits the 256MiB L3).
// Horizontal: 11-tap via 10 __shfl + edge reflect fixups, sliding-sum ->
//           4 outputs -> one nontemporal float4 store (output never re-read).

typedef float f32x4 __attribute__((ext_vector_type(4)));

#define PAD   5
#define IMG   256
#define STRIP 32
#define PRE   (2 * PAD)          // 10 priming iterations
#define ITERS (STRIP + PRE)      // 42

__device__ __forceinline__ int refl(int r) {
    return (r < 0) ? -r : ((r > IMG - 1) ? 2 * (IMG - 1) - r : r);
}

__global__ __launch_bounds__(256, 8)
void blur_box11_kernel(const float* __restrict__ in,
                       const float* __restrict__ kern,
                       float* __restrict__ out) {
    const int lane = threadIdx.x & 63;
    const int wv   = threadIdx.x >> 6;             // 0..3
    const int img  = blockIdx.x >> 1;              // 0..1023
    const int half = blockIdx.x & 1;               // 0..1
    const int S    = half * 128 + wv * STRIP;      // strip's first output row
    const int X0   = lane * 4;                     // lane's 4 columns

    const float* src = in  + (size_t)img * (IMG * IMG);
    float*       dst = out + (size_t)img * (IMG * IMG);
    const float  kv  = kern[0];                    // 1/121 (uniform box)

#define LOADROW(i) (*reinterpret_cast<const f32x4*>( \
        src + (size_t)refl(S - PAD + (i)) * IMG + X0))

    f32x4 ring[11];
#pragma unroll
    for (int k = 0; k < 11; ++k) ring[k] = (f32x4)0.0f;
    f32x4 cs = (f32x4)0.0f;

    f32x4 va = LOADROW(0);                         // 2-deep prefetch pipeline
    f32x4 vb = LOADROW(1);

#pragma unroll
    for (int i = 0; i < ITERS; ++i) {              // full unroll: ring idx static
        f32x4 v = va;
        va = vb;
        if (i + 2 < ITERS) vb = LOADROW(i + 2);

        cs += v - ring[i % 11];                    // vertical sliding 11-sum
        ring[i % 11] = v;

        if (i >= PRE) {
            const int row = S + i - PRE;           // output row S..S+31

            // assemble cols X0-5 .. X0+8 (v0..v13) in registers
            float v0  = __shfl(cs.w, lane - 2);
            float v1  = __shfl(cs.x, lane - 1);
            float v2  = __shfl(cs.y, lane - 1);
            float v3  = __shfl(cs.z, lane - 1);
            float v4  = __shfl(cs.w, lane - 1);
            float v5  = cs.x, v6 = cs.y, v7 = cs.z, v8 = cs.w;
            float v9  = __shfl(cs.x, lane + 1);
            float v10 = __shfl(cs.y, lane + 1);
            float v11 = __shfl(cs.z, lane + 1);
            float v12 = __shfl(cs.w, lane + 1);
            float v13 = __shfl(cs.x, lane + 2);

            // reflect fixups (also repair out-of-range shuffle slots)
            if (lane == 0)       { v0 = v10; v1 = v9; v2 = v8; v3 = v7; v4 = v6; }
            else if (lane == 1)  { v0 = v2; }
            if (lane == 63)      { v9 = v7; v10 = v6; v11 = v5; v12 = v4; v13 = v3; }
            else if (lane == 62) { v13 = v11; }

            // sliding 11-sum over the 14-col window -> 4 outputs
            float s0 = ((v0 + v1) + (v2 + v3)) + ((v4 + v5) + (v6 + v7))
                     + ((v8 + v9) + v10);
            float s1 = s0 - v0 + v11;
            float s2 = s1 - v1 + v12;
            float s3 = s2 - v2 + v13;

            f32x4 o;
            o.x = s0 * kv; o.y = s1 * kv; o.z = s2 * kv; o.w = s3 * kv;
            __builtin_nontemporal_store(
                o, reinterpret_cast<f32x4*>(dst + (size_t)row * IMG + X0));
        }
    }
#undef LOADROW
}

extern "C" void kernel_launch(void* const* d_in, const int* in_sizes, int n_in,
                              void* d_out, int out_size, void* d_ws, size_t ws_size,
                              hipStream_t stream) {
    const float* in   = (const float*)d_in[0];
    const float* kern = (const float*)d_in[1];
    float*       out  = (float*)d_out;

    const int n_images = 16 * 64;                  // B * C
    dim3 grid(n_images * 2);                       // 2048 blocks, 4 waves each
    dim3 block(256);
    blur_box11_kernel<<<grid, block, 0, stream>>>(in, kern, out);
}

// Round 7
// 89.586 us; speedup vs baseline: 2.0972x; 2.0972x over previous
//
#include <hip/hip_runtime.h>

// Depthwise 11x11 box blur, reflect pad, fp32, (16,64,256,256).
// Separable, register-resident vertical ring + shuffle horizontal.
// NO LDS data plane, NO barriers.
//
// Round-7: round-5 structure (strip 64, grid 1024, launch_bounds(256,4) ->
// no spill; round 6 proved (256,8) demotes the ring to scratch: VGPR 48->32,
// FETCH 147->304MB, 2x regression). Single lever vs round 5: explicit load
// prefetch depth 2 -> 4 (q0..q3), doubling in-flight bytes per wave
// (2KB -> 4KB/wave, 64KB/CU at 16 waves) to cover ~900ns HBM latency.
// BW saturation here is per-wave MLP, not occupancy: the harness's own
// 1GiB fills hit 7TB/s at 10% occupancy.
//
// Vertical: 11-deep float4 register ring, fully unrolled (static indices).
//           Reads/byte = 74/64 = 1.16x.
// Horizontal: 11-tap via 10 __shfl + edge reflect fixups, sliding-sum ->
//           4 outputs -> one nontemporal float4 store (output never re-read).

typedef float f32x4 __attribute__((ext_vector_type(4)));

#define PAD   5
#define IMG   256
#define STRIP 64
#define PRE   (2 * PAD)          // 10 priming iterations
#define ITERS (STRIP + PRE)      // 74
#define MLP   4                  // prefetch depth

__device__ __forceinline__ int refl(int r) {
    return (r < 0) ? -r : ((r > IMG - 1) ? 2 * (IMG - 1) - r : r);
}

__global__ __launch_bounds__(256, 4)
void blur_box11_kernel(const float* __restrict__ in,
                       const float* __restrict__ kern,
                       float* __restrict__ out) {
    const int lane = threadIdx.x & 63;
    const int wv   = threadIdx.x >> 6;             // 0..3
    const int img  = blockIdx.x;                   // 0..1023
    const int S    = wv * STRIP;                   // strip's first output row
    const int X0   = lane * 4;                     // lane's 4 columns

    const float* src = in  + (size_t)img * (IMG * IMG);
    float*       dst = out + (size_t)img * (IMG * IMG);
    const float  kv  = kern[0];                    // 1/121 (uniform box)

#define LOADROW(i) (*reinterpret_cast<const f32x4*>( \
        src + (size_t)refl(S - PAD + (i)) * IMG + X0))

    f32x4 ring[11];
#pragma unroll
    for (int k = 0; k < 11; ++k) ring[k] = (f32x4)0.0f;
    f32x4 cs = (f32x4)0.0f;

    // 4-deep prefetch pipeline: 4 outstanding 1KB loads per wave
    f32x4 q0 = LOADROW(0);
    f32x4 q1 = LOADROW(1);
    f32x4 q2 = LOADROW(2);
    f32x4 q3 = LOADROW(3);

#pragma unroll
    for (int i = 0; i < ITERS; ++i) {              // full unroll: ring idx static
        f32x4 v = q0;
        q0 = q1; q1 = q2; q2 = q3;
        if (i + MLP < ITERS) q3 = LOADROW(i + MLP);

        cs += v - ring[i % 11];                    // vertical sliding 11-sum
        ring[i % 11] = v;

        if (i >= PRE) {
            const int row = S + i - PRE;           // output row S..S+63

            // assemble cols X0-5 .. X0+8 (v0..v13) in registers
            float v0  = __shfl(cs.w, lane - 2);
            float v1  = __shfl(cs.x, lane - 1);
            float v2  = __shfl(cs.y, lane - 1);
            float v3  = __shfl(cs.z, lane - 1);
            float v4  = __shfl(cs.w, lane - 1);
            float v5  = cs.x, v6 = cs.y, v7 = cs.z, v8 = cs.w;
            float v9  = __shfl(cs.x, lane + 1);
            float v10 = __shfl(cs.y, lane + 1);
            float v11 = __shfl(cs.z, lane + 1);
            float v12 = __shfl(cs.w, lane + 1);
            float v13 = __shfl(cs.x, lane + 2);

            // reflect fixups (also repair out-of-range shuffle slots)
            if (lane == 0)       { v0 = v10; v1 = v9; v2 = v8; v3 = v7; v4 = v6; }
            else if (lane == 1)  { v0 = v2; }
            if (lane == 63)      { v9 = v7; v10 = v6; v11 = v5; v12 = v4; v13 = v3; }
            else if (lane == 62) { v13 = v11; }

            // sliding 11-sum over the 14-col window -> 4 outputs
            float s0 = ((v0 + v1) + (v2 + v3)) + ((v4 + v5) + (v6 + v7))
                     + ((v8 + v9) + v10);
            float s1 = s0 - v0 + v11;
            float s2 = s1 - v1 + v12;
            float s3 = s2 - v2 + v13;

            f32x4 o;
            o.x = s0 * kv; o.y = s1 * kv; o.z = s2 * kv; o.w = s3 * kv;
            __builtin_nontemporal_store(
                o, reinterpret_cast<f32x4*>(dst + (size_t)row * IMG + X0));
        }
    }
#undef LOADROW
}

extern "C" void kernel_launch(void* const* d_in, const int* in_sizes, int n_in,
                              void* d_out, int out_size, void* d_ws, size_t ws_size,
                              hipStream_t stream) {
    const float* in   = (const float*)d_in[0];
    const float* kern = (const float*)d_in[1];
    float*       out  = (float*)d_out;

    const int n_images = 16 * 64;                  // B * C
    dim3 grid(n_images);                           // 1024 blocks, 4 waves each
    dim3 block(256);
    blur_box11_kernel<<<grid, block, 0, stream>>>(in, kern, out);
}